// Round 2
// baseline (4158.334 us; speedup 1.0000x reference)
//
#include <hip/hip_runtime.h>
#include <hip/hip_bf16.h>
#include <stdint.h>

// Problem constants
#define B_   64
#define S_   512
#define DIN  512
#define DH   1024
#define NBG  4               // batch groups (16 batches each)
#define NCG  32              // col groups (32 cols each)
#define BBLK 16
#define CBLK 32
#define NKC  48              // total k-chunks of 32 (16 x-chunks + 32 h-chunks)

typedef __bf16 bf16x8 __attribute__((ext_vector_type(8)));
typedef float f32x4 __attribute__((ext_vector_type(4)));
typedef unsigned short ushort8v __attribute__((ext_vector_type(8)));
typedef unsigned short ushort4v __attribute__((ext_vector_type(4)));

static __device__ __forceinline__ unsigned short f2bf(float f) {
    union { __bf16 b; unsigned short u; } v; v.b = (__bf16)f; return v.u;
}
static __device__ __forceinline__ float fast_tanh(float x) {
    // 1 - 2/(e^{2x}+1): exact at +/-inf, no NaN from inf/inf
    float e = __expf(2.0f * x);
    return 1.0f - 2.0f / (e + 1.0f);
}

// ---------------- convert x (fp32 -> bf16), 4 elems/thread ----------------
__global__ void k_cvt_bf16(const float* __restrict__ src,
                           unsigned short* __restrict__ dst, int n4) {
    int i = blockIdx.x * blockDim.x + threadIdx.x;
    if (i < n4) {
        float4 v = ((const float4*)src)[i];
        ushort4v o;
        o.x = f2bf(v.x); o.y = f2bf(v.y); o.z = f2bf(v.z); o.w = f2bf(v.w);
        ((ushort4v*)dst)[i] = o;
    }
}

// ------- swizzle W (fp32 [1536][1024]) into B-fragment order, bf16 -------
// layout: [kc(48)][ntg(64)][lane(64)][8] ; frag elem i = W[kc*32+q*8+i][ntg*16+n16]
__global__ void k_swz_w(const float* __restrict__ W,
                        unsigned short* __restrict__ dst) {
    int u = blockIdx.x * blockDim.x + threadIdx.x;   // 48*64*64 = 196608
    int lane = u & 63;
    int ntg  = (u >> 6) & 63;
    int kc   = u >> 12;
    int q = lane >> 4, n16 = lane & 15;
    int k0 = kc * 32 + q * 8;
    int n  = ntg * 16 + n16;
    ushort8v o;
#pragma unroll
    for (int i = 0; i < 8; ++i) o[i] = f2bf(W[(size_t)(k0 + i) * DH + n]);
    *(ushort8v*)(dst + (size_t)u * 8) = o;
}

// ---------------- persistent recurrence kernel ----------------
// LDS: h-staging (16 rows x 1024 + 8 pad) + 4-wave partials
#define H_PITCH 1032

__global__ __launch_bounds__(256, 1) void k_rnn(
    const unsigned short* __restrict__ xb,    // [B][S][DIN] bf16
    const unsigned short* __restrict__ wswz,  // swizzled W bf16
    const float* __restrict__ h0,             // [B][DH] fp32
    const float* __restrict__ bias,           // [DH] fp32
    float* __restrict__ out,                  // outs [B][S][DH] + h_last [B][DH]
    unsigned int* ring,                       // [2][B][DH/2] bf16-pairs
    int* flags)                               // [NBG][S][32] one per producer
{
    __shared__ unsigned short ldsH[16 * H_PITCH];   // 33 KB
    __shared__ float ldsP[4 * 512];                 // 8 KB

    const int tid = threadIdx.x;
    const int bg = blockIdx.x >> 5;
    const int cg = blockIdx.x & 31;
    const int b0 = bg * BBLK;
    const int c0 = cg * CBLK;
    const int lane = tid & 63;
    const int wv = tid >> 6;
    const int q = lane >> 4;
    const int m16 = lane & 15;

    // ---- one-time: W fragments into REGISTERS (per wave: 4 x-kc + 8 h-kc, 2 n-tiles)
    // wswz frag addr: ((kc*64 + 2*cg + l)*64 + lane)*8
    bf16x8 wx[4][2], wh[8][2];
#pragma unroll
    for (int j = 0; j < 4; ++j) {
        int kc = 4 * wv + j;
#pragma unroll
        for (int l = 0; l < 2; ++l)
            wx[j][l] = *(const bf16x8*)(wswz + ((size_t)(kc * 64 + 2 * cg + l) * 64 + lane) * 8);
    }
#pragma unroll
    for (int j = 0; j < 8; ++j) {
        int kc = 16 + 8 * wv + j;
#pragma unroll
        for (int l = 0; l < 2; ++l)
            wh[j][l] = *(const bf16x8*)(wswz + ((size_t)(kc * 64 + 2 * cg + l) * 64 + lane) * 8);
    }

    // ---- x A-fragment base: row (b0+m16), cols (4wv+j)*32 + q*8, time t
    const unsigned short* xbase =
        xb + (size_t)(b0 + m16) * S_ * DIN + (4 * wv) * 32 + q * 8;
    bf16x8 xf[4];
#pragma unroll
    for (int j = 0; j < 4; ++j)           // prefetch t=0
        xf[j] = *(const bf16x8*)(xbase + j * 32);

    const int em = tid >> 4;              // epilogue row 0..15
    const int np = (tid & 15) * 2;        // epilogue col pair
    const float bias0 = bias[c0 + np];
    const float bias1 = bias[c0 + np + 1];

    for (int t = 0; t < S_; ++t) {
        // ---- x-part MFMAs first: independent of peers (xf prefetched last step)
        f32x4 acc0 = {0.f, 0.f, 0.f, 0.f}, acc1 = {0.f, 0.f, 0.f, 0.f};
#pragma unroll
        for (int j = 0; j < 4; ++j) {
            acc0 = __builtin_amdgcn_mfma_f32_16x16x32_bf16(xf[j], wx[j][0], acc0, 0, 0, 0);
            acc1 = __builtin_amdgcn_mfma_f32_16x16x32_bf16(xf[j], wx[j][1], acc1, 0, 0, 0);
        }

        // ---- wait for h_{t-1}: every wave ballot-polls the 32 producer flags
        if (t > 0) {
            const int* fp = flags + (((size_t)bg * S_ + (t - 1)) << 5) + (lane & 31);
            for (;;) {
                int f = __hip_atomic_load(fp, __ATOMIC_RELAXED, __HIP_MEMORY_SCOPE_AGENT);
                if (__ballot(f == 0) == 0) break;
            }
            __builtin_amdgcn_fence(__ATOMIC_ACQUIRE, "agent");
        }

        // ---- stage h_{t-1} -> ldsH (bf16 pairs; uint2 granules)
        if (t == 0) {
#pragma unroll
            for (int row = 0; row < 16; ++row) {
                float4 v = *(const float4*)(h0 + (size_t)(b0 + row) * DH + tid * 4);
                unsigned int p0 = (unsigned int)f2bf(v.x) | ((unsigned int)f2bf(v.y) << 16);
                unsigned int p1 = (unsigned int)f2bf(v.z) | ((unsigned int)f2bf(v.w) << 16);
                uint2 pk; pk.x = p0; pk.y = p1;
                *(uint2*)(ldsH + row * H_PITCH + tid * 4) = pk;
            }
        } else {
            const unsigned long long* rg =
                (const unsigned long long*)(ring + ((t - 1) & 1) * (B_ * (DH / 2)));
            unsigned long long hv[16];
#pragma unroll
            for (int row = 0; row < 16; ++row)      // issue all loads first (ILP)
                hv[row] = __hip_atomic_load(rg + ((size_t)(b0 + row) * 512 + tid * 2) / 2,
                                            __ATOMIC_RELAXED, __HIP_MEMORY_SCOPE_AGENT);
#pragma unroll
            for (int row = 0; row < 16; ++row)
                *(unsigned long long*)(ldsH + row * H_PITCH + tid * 4) = hv[row];
        }
        __syncthreads();   // A: h staged

        // ---- h-part MFMAs (per wave: 8 k-chunks x 2 n-tiles), A from LDS, B from regs
#pragma unroll
        for (int j = 0; j < 8; ++j) {
            bf16x8 a = *(const bf16x8*)(ldsH + m16 * H_PITCH + (8 * wv + j) * 32 + q * 8);
            acc0 = __builtin_amdgcn_mfma_f32_16x16x32_bf16(a, wh[j][0], acc0, 0, 0, 0);
            acc1 = __builtin_amdgcn_mfma_f32_16x16x32_bf16(a, wh[j][1], acc1, 0, 0, 0);
        }
#pragma unroll
        for (int i = 0; i < 4; ++i) {
            ldsP[wv * 512 + (q * 4 + i) * 32 + m16]      = acc0[i];
            ldsP[wv * 512 + (q * 4 + i) * 32 + 16 + m16] = acc1[i];
        }
        __syncthreads();   // B: partials ready

        // ---- epilogue: reduce 4 wave-partials, bias, tanh
        float s0 = bias0, s1 = bias1;
#pragma unroll
        for (int w = 0; w < 4; ++w) {
            const float2 p = *(const float2*)(ldsP + w * 512 + em * 32 + np);
            s0 += p.x; s1 += p.y;
        }
        float v0 = fast_tanh(s0), v1 = fast_tanh(s1);
        unsigned int pk = (unsigned int)f2bf(v0) | ((unsigned int)f2bf(v1) << 16);

        // ---- publish h_t: data stores -> barrier (drains acks) -> per-producer flag
        unsigned int* rw = ring + (t & 1) * (B_ * (DH / 2));
        __hip_atomic_store(rw + (size_t)(b0 + em) * 512 + (c0 + np) / 2, pk,
                           __ATOMIC_RELAXED, __HIP_MEMORY_SCOPE_AGENT);
        __syncthreads();   // C: all ring stores complete (implicit vmcnt(0))
        if (tid == 0)
            __hip_atomic_store(flags + (((size_t)bg * S_ + t) << 5) + cg, 1,
                               __ATOMIC_RELEASE, __HIP_MEMORY_SCOPE_AGENT);

        // ---- off the critical path: out store + next-step x prefetch
        float2 ov; ov.x = v0; ov.y = v1;
        *(float2*)(out + ((size_t)(b0 + em) * S_ + t) * DH + c0 + np) = ov;
        if (t == S_ - 1)
            *(float2*)(out + (size_t)B_ * S_ * DH + (size_t)(b0 + em) * DH + c0 + np) = ov;

        if (t < S_ - 1) {
            const unsigned short* xp = xbase + (size_t)(t + 1) * DIN;
#pragma unroll
            for (int j = 0; j < 4; ++j)
                xf[j] = *(const bf16x8*)(xp + j * 32);
        }
    }
}

extern "C" void kernel_launch(void* const* d_in, const int* in_sizes, int n_in,
                              void* d_out, int out_size, void* d_ws, size_t ws_size,
                              hipStream_t stream) {
    const float* x  = (const float*)d_in[0];   // [64][512][512]
    const float* h0 = (const float*)d_in[1];   // [64][1024]
    const float* W  = (const float*)d_in[2];   // [1536][1024]
    const float* b  = (const float*)d_in[3];   // [1024]
    float* out = (float*)d_out;

    // workspace layout
    char* ws = (char*)d_ws;
    int* flags = (int*)ws;                                          // 256 KB
    unsigned int* ring = (unsigned int*)(ws + (256 << 10));         // 256 KB
    unsigned short* xb = (unsigned short*)(ws + (512 << 10));       // 32 MB
    unsigned short* wswz = xb + (size_t)B_ * S_ * DIN;              // 3 MB

    hipMemsetAsync(flags, 0, NBG * S_ * 32 * sizeof(int), stream);
    k_cvt_bf16<<<(B_ * S_ * DIN / 4 + 255) / 256, 256, 0, stream>>>(x, xb, B_ * S_ * DIN / 4);
    k_swz_w<<<(NKC * 64 * 64) / 256, 256, 0, stream>>>(W, wswz);
    k_rnn<<<NBG * NCG, 256, 0, stream>>>(xb, wswz, h0, b, out, ring, flags);
}